// Round 1
// baseline (213.566 us; speedup 1.0000x reference)
//
#include <hip/hip_runtime.h>

// SimpleRNN fused kernel for MI355X (gfx950).
// B=32768, T=28, I=28, H=128, C=10.
//
// Orientation trick: compute pre-activation TRANSPOSED, D[h][b] = W * S^T:
//   - A-operand = W (m = h_out), resident in VGPRs (bf16 frags, loaded once)
//   - B-operand = S^T streamed from LDS (k = h_in contiguous per lane -> b64 reads)
//   - D rows (register-contiguous, 4 consecutive h) pack into b64 LDS writes of
//     row-major S[b][h] -> no transpose needed between steps.
// MFMA 16x16x32 bf16 layouts (HW-verified per guide m89/m91/m120):
//   A: A[m = lane&15][k = (lane>>4)*8 + j], j=0..7
//   B: B[k = (lane>>4)*8 + j][n = lane&15]
//   D: D[(lane>>4)*4 + reg][lane&15]
// Block: 256 threads = 4 waves, BM=64 batch rows, grid 512 = 2 blocks/CU.
// Wave w: h-half = (w>>1)*64 (4 m-tiles), batch-half = (w&1)*32 (2 n-tiles).
// LDS: double-buffered S[64][132] bf16 (stride 132: b64 reads/writes conflict-free,
// rows 8B-aligned). 2*8448*2 = 33792 B/block -> 2 blocks/CU fits 160 KB.

#define T_STEPS 28
#define I_DIM   28
#define S_STRIDE 132

typedef __attribute__((ext_vector_type(4))) float f32x4;
typedef __attribute__((ext_vector_type(8))) short short8;

#define MFMA16 __builtin_amdgcn_mfma_f32_16x16x32_bf16

__device__ __forceinline__ unsigned short f2bf(float f) {
  unsigned u = __builtin_bit_cast(unsigned, f);
  u += 0x7FFFu + ((u >> 16) & 1u);   // RNE to bf16
  return (unsigned short)(u >> 16);
}
__device__ __forceinline__ float bf2f(unsigned short s) {
  return __builtin_bit_cast(float, (unsigned)s << 16);
}

__device__ __forceinline__ short8 to_frag(f32x4 a, f32x4 b) {
  union { unsigned short u[8]; short8 v; } r;
#pragma unroll
  for (int j = 0; j < 4; ++j) { r.u[j] = f2bf(a[j]); r.u[j + 4] = f2bf(b[j]); }
  return r.v;
}

__device__ __forceinline__ short8 load_sfrag(const unsigned short* sp, int off) {
  // 8 consecutive bf16 (16 B) as two b64 reads (rows are 8B- but not 16B-aligned)
  union { uint2 d[2]; short8 v; } r;
  r.d[0] = *(const uint2*)(sp + off);
  r.d[1] = *(const uint2*)(sp + off + 4);
  return r.v;
}

__device__ __forceinline__ float fast_tanh(float z) {
  // tanh(z) = 1 - 2/(exp(2z)+1); v_exp + v_rcp, ~1e-6 abs error (<< bf16 state noise)
  float e = __expf(2.0f * z);
#if __has_builtin(__builtin_amdgcn_rcpf)
  return 1.0f - 2.0f * __builtin_amdgcn_rcpf(e + 1.0f);
#else
  return 1.0f - 2.0f / (e + 1.0f);
#endif
}

__global__ __launch_bounds__(256, 2) void rnn_fused(
    const float* __restrict__ x,  const float* __restrict__ Uw,
    const float* __restrict__ Ub, const float* __restrict__ Ww,
    const float* __restrict__ Wb, const float* __restrict__ Vw,
    const float* __restrict__ Vb, float* __restrict__ out) {
  __shared__ unsigned short Sbuf[2][64 * S_STRIDE];

  const int tid  = threadIdx.x;
  const int w    = tid >> 6;
  const int lane = tid & 63;
  const int l15  = lane & 15;
  const int q    = lane >> 4;           // 0..3
  const int mrow = (w >> 1) * 64;       // h base for this wave
  const int ncol = (w & 1) * 32;        // batch base within block
  const int b0   = blockIdx.x * 64;

  const f32x4 zero4 = {0.f, 0.f, 0.f, 0.f};

  // ---- persistent register fragments: W (A-op), U (A-op), bias ----
  short8 wfrag[4][4];   // [mt][kt]
  short8 ufrag[4];      // [mt], K=32 padded (i>=28 zero)
  f32x4  bias[4];       // Ub[h]+Wb[h] at D rows h = mrow + mt*16 + q*4 + r
#pragma unroll
  for (int mt = 0; mt < 4; ++mt) {
    const int h = mrow + mt * 16 + l15;
    const float* wp = Ww + h * 128 + q * 8;
#pragma unroll
    for (int kt = 0; kt < 4; ++kt) {
      wfrag[mt][kt] = to_frag(*(const f32x4*)wp, *(const f32x4*)(wp + 4));
      wp += 32;
    }
    const float* up = Uw + h * I_DIM + q * 8;
    f32x4 u0 = *(const f32x4*)up;
    f32x4 u1 = zero4;
    if (q < 3) u1 = *(const f32x4*)(up + 4);
    ufrag[mt] = to_frag(u0, u1);
    const int hb = mrow + mt * 16 + q * 4;
    bias[mt] = *(const f32x4*)(Wb + hb) + *(const f32x4*)(Ub + hb);
  }

  // x pointers: B-operand frag, n = batch = lane&15, k = i = q*8+j
  const float* xptr[2];
#pragma unroll
  for (int nt = 0; nt < 2; ++nt)
    xptr[nt] = x + (size_t)(b0 + ncol + nt * 16 + l15) * (T_STEPS * I_DIM) + q * 8;

  // LDS element offsets
  int ro[2];
#pragma unroll
  for (int nt = 0; nt < 2; ++nt) ro[nt] = (ncol + nt * 16 + l15) * S_STRIDE;

  f32x4 acc[4][2];

  // ---- t = 0 (S=0: projection only) ----
  {
    f32x4 xa[2], xbv[2];
#pragma unroll
    for (int nt = 0; nt < 2; ++nt) {
      xa[nt] = *(const f32x4*)xptr[nt];
      xbv[nt] = zero4;
      if (q < 3) xbv[nt] = *(const f32x4*)(xptr[nt] + 4);
      xptr[nt] += I_DIM;
    }
    short8 xf0 = to_frag(xa[0], xbv[0]);
    short8 xf1 = to_frag(xa[1], xbv[1]);
#pragma unroll
    for (int mt = 0; mt < 4; ++mt) {
      acc[mt][0] = MFMA16(ufrag[mt], xf0, zero4, 0, 0, 0);
      acc[mt][1] = MFMA16(ufrag[mt], xf1, zero4, 0, 0, 0);
    }
    unsigned short* wp = &Sbuf[1][0];
#pragma unroll
    for (int mt = 0; mt < 4; ++mt)
#pragma unroll
      for (int nt = 0; nt < 2; ++nt) {
        f32x4 z = acc[mt][nt] + bias[mt];
        unsigned s0 = f2bf(fast_tanh(z[0]));
        unsigned s1 = f2bf(fast_tanh(z[1]));
        unsigned s2 = f2bf(fast_tanh(z[2]));
        unsigned s3 = f2bf(fast_tanh(z[3]));
        uint2 d; d.x = s0 | (s1 << 16); d.y = s2 | (s3 << 16);
        *(uint2*)(wp + ro[nt] + mrow + mt * 16 + q * 4) = d;
      }
  }
  __syncthreads();

  // ---- t = 1 .. 27 ----
#pragma unroll 1
  for (int t = 1; t < T_STEPS; ++t) {
    // issue x loads early (covered by the recurrence MFMAs below)
    f32x4 xa[2], xbv[2];
#pragma unroll
    for (int nt = 0; nt < 2; ++nt) {
      xa[nt] = *(const f32x4*)xptr[nt];
      xbv[nt] = zero4;
      if (q < 3) xbv[nt] = *(const f32x4*)(xptr[nt] + 4);
      xptr[nt] += I_DIM;
    }

    const unsigned short* sp = &Sbuf[t & 1][0];
#pragma unroll
    for (int mt = 0; mt < 4; ++mt) { acc[mt][0] = zero4; acc[mt][1] = zero4; }

#pragma unroll
    for (int kt = 0; kt < 4; ++kt) {
      short8 s0 = load_sfrag(sp, ro[0] + kt * 32 + q * 8);
      short8 s1 = load_sfrag(sp, ro[1] + kt * 32 + q * 8);
#pragma unroll
      for (int mt = 0; mt < 4; ++mt) {
        acc[mt][0] = MFMA16(wfrag[mt][kt], s0, acc[mt][0], 0, 0, 0);
        acc[mt][1] = MFMA16(wfrag[mt][kt], s1, acc[mt][1], 0, 0, 0);
      }
    }

    short8 xf0 = to_frag(xa[0], xbv[0]);
    short8 xf1 = to_frag(xa[1], xbv[1]);
#pragma unroll
    for (int mt = 0; mt < 4; ++mt) {
      acc[mt][0] = MFMA16(ufrag[mt], xf0, acc[mt][0], 0, 0, 0);
      acc[mt][1] = MFMA16(ufrag[mt], xf1, acc[mt][1], 0, 0, 0);
    }

    unsigned short* wp = &Sbuf[(t + 1) & 1][0];
#pragma unroll
    for (int mt = 0; mt < 4; ++mt)
#pragma unroll
      for (int nt = 0; nt < 2; ++nt) {
        f32x4 z = acc[mt][nt] + bias[mt];
        unsigned s0 = f2bf(fast_tanh(z[0]));
        unsigned s1 = f2bf(fast_tanh(z[1]));
        unsigned s2 = f2bf(fast_tanh(z[2]));
        unsigned s3 = f2bf(fast_tanh(z[3]));
        uint2 d; d.x = s0 | (s1 << 16); d.y = s2 | (s3 << 16);
        *(uint2*)(wp + ro[nt] + mrow + mt * 16 + q * 4) = d;
      }
    __syncthreads();
  }

  // ---- epilogue: out[b][c] = sum_h S[b][h] * Vw[c][h] + Vb[c] ----
  // Final S is in Sbuf[(27+1)&1] = Sbuf[0]. 64 rows x 10 cols per block.
  {
    const unsigned short* sf = &Sbuf[0][0];
    const int r  = tid >> 2;        // 0..63
    const int c0 = tid & 3;         // cols c0, c0+4, (c0+8 if c0<2)
    const float* v0 = Vw + c0 * 128;
    const float* v1 = Vw + (c0 + 4) * 128;
    const float* v2 = Vw + ((c0 & 1) + 8) * 128;   // safe row even when unused
    const unsigned short* srow = sf + r * S_STRIDE;
    float a0 = 0.f, a1 = 0.f, a2 = 0.f;
#pragma unroll 8
    for (int h = 0; h < 128; ++h) {
      float s = bf2f(srow[h]);
      a0 += s * v0[h];
      a1 += s * v1[h];
      a2 += s * v2[h];
    }
    float* op = out + (size_t)(b0 + r) * 10;
    op[c0]     = a0 + Vb[c0];
    op[c0 + 4] = a1 + Vb[c0 + 4];
    if (c0 < 2) op[c0 + 8] = a2 + Vb[c0 + 8];
  }
}

extern "C" void kernel_launch(void* const* d_in, const int* in_sizes, int n_in,
                              void* d_out, int out_size, void* d_ws, size_t ws_size,
                              hipStream_t stream) {
  const float* x  = (const float*)d_in[0];
  const float* Uw = (const float*)d_in[1];
  const float* Ub = (const float*)d_in[2];
  const float* Ww = (const float*)d_in[3];
  const float* Wb = (const float*)d_in[4];
  const float* Vw = (const float*)d_in[5];
  const float* Vb = (const float*)d_in[6];
  rnn_fused<<<512, 256, 0, stream>>>(x, Uw, Ub, Ww, Wb, Vw, Vb, (float*)d_out);
}